// Round 1
// baseline (270.805 us; speedup 1.0000x reference)
//
#include <hip/hip_runtime.h>

typedef unsigned short u16;
typedef __attribute__((ext_vector_type(8))) short bf16x8;
typedef __attribute__((ext_vector_type(4))) float f32x4;

#define MFMA16(a, b, c) __builtin_amdgcn_mfma_f32_16x16x32_bf16(a, b, c, 0, 0, 0)

__device__ inline u16 f2bf(float f) {
    unsigned u = __float_as_uint(f);
    u = u + 0x7FFFu + ((u >> 16) & 1u);
    return (u16)(u >> 16);
}

// ---------------- weight conversion: qkv_w (384x256) + proj_w (256x128) -> bf16
__global__ __launch_bounds__(256) void k_wconv(const float* qw, const float* pw, u16* qwb, u16* pwb) {
    int tid = blockIdx.x * 256 + threadIdx.x;
    int base = tid * 8;
    const float* src;
    u16* dst;
    if (base < 98304) { src = qw + base; dst = qwb + base; }
    else { src = pw + (base - 98304); dst = pwb + (base - 98304); }
    float4 v0 = *(const float4*)(src);
    float4 v1 = *(const float4*)(src + 4);
    ushort4 o0, o1;
    o0.x = f2bf(v0.x); o0.y = f2bf(v0.y); o0.z = f2bf(v0.z); o0.w = f2bf(v0.w);
    o1.x = f2bf(v1.x); o1.y = f2bf(v1.y); o1.z = f2bf(v1.z); o1.w = f2bf(v1.w);
    *(ushort4*)(dst) = o0;
    *(ushort4*)(dst + 4) = o1;
}

// ---------------- groupnorm stats stage 1: per (group, split) partial sums
// grid 256: gi = bid>>4 (16 groups = B*8), s = bid&15. Each block sums 8192 contiguous floats.
__global__ __launch_bounds__(256) void k_stats1(const float* x, float* psum, float* psumsq) {
    int bid = blockIdx.x;
    int gi = bid >> 4, s = bid & 15;
    const float* base = x + (size_t)gi * 131072 + s * 8192;
    int t = threadIdx.x;
    float s1 = 0.f, s2 = 0.f;
#pragma unroll
    for (int it = 0; it < 8; it++) {
        float4 v = *(const float4*)(base + it * 1024 + t * 4);
        s1 += (v.x + v.y) + (v.z + v.w);
        s2 += (v.x * v.x + v.y * v.y) + (v.z * v.z + v.w * v.w);
    }
    for (int msk = 1; msk < 64; msk <<= 1) {
        s1 += __shfl_xor(s1, msk);
        s2 += __shfl_xor(s2, msk);
    }
    __shared__ float r1[4], r2[4];
    int w = t >> 6;
    if ((t & 63) == 0) { r1[w] = s1; r2[w] = s2; }
    __syncthreads();
    if (t == 0) {
        psum[bid] = (r1[0] + r1[1]) + (r1[2] + r1[3]);
        psumsq[bid] = (r2[0] + r2[1]) + (r2[2] + r2[3]);
    }
}

// ---------------- groupnorm stats stage 2: finalize 16 groups
__global__ void k_stats2(const float* psum, const float* psumsq, float* meanb, float* rstdb) {
    int t = threadIdx.x;
    if (t < 16) {
        float s1 = 0.f, s2 = 0.f;
        for (int i = 0; i < 16; i++) { s1 += psum[t * 16 + i]; s2 += psumsq[t * 16 + i]; }
        float mu = s1 * (1.0f / 131072.0f);
        float var = s2 * (1.0f / 131072.0f) - mu * mu;
        meanb[t] = mu;
        rstdb[t] = rsqrtf(var + 1e-5f);
    }
}

// ---------------- normalize + transpose: x (b,c,n) f32 -> xnt (b,n,c) bf16
// grid 2048: b = bid>>10, ct = (bid>>7)&7, nt = bid&127. 32c x 32n tile per block.
__global__ __launch_bounds__(256) void k_normt(const float* x, const float* gw, const float* gb,
                                               const float* meanb, const float* rstdb, u16* xnt) {
    int bid = blockIdx.x;
    int b = bid >> 10, ct = (bid >> 7) & 7, nt = bid & 127;
    int t = threadIdx.x;
    int r = t >> 3, q = t & 7;
    __shared__ float tile[32][33];
    int gi = b * 8 + ct;                 // group index (32 channels per group == tile)
    float mu = meanb[gi], rs = rstdb[gi];
    int c = ct * 32 + r;
    float wv = gw[c] * rs;
    float bv = gb[c] - mu * wv;
    float4 v = *(const float4*)(x + ((size_t)(b * 256 + c)) * 4096 + nt * 32 + q * 4);
    tile[r][q * 4 + 0] = v.x * wv + bv;
    tile[r][q * 4 + 1] = v.y * wv + bv;
    tile[r][q * 4 + 2] = v.z * wv + bv;
    tile[r][q * 4 + 3] = v.w * wv + bv;
    __syncthreads();
    int cq = q * 4;
    ushort4 o;
    o.x = f2bf(tile[cq + 0][r]);
    o.y = f2bf(tile[cq + 1][r]);
    o.z = f2bf(tile[cq + 2][r]);
    o.w = f2bf(tile[cq + 3][r]);
    *(ushort4*)(xnt + ((size_t)(b * 4096 + nt * 32 + r)) * 256 + ct * 32 + cq) = o;
}

// ---------------- QKV GEMM: qkv_w(384x256) x xnt^T -> q,k transposed (b,n,256) ; v natural (b,128,n)
// grid 192 = b(2) x mt(3) x nt(32). 128x128 tile, 4 waves, each 64x64 (4x4 frags).
__global__ __launch_bounds__(256) void k_qkv(const u16* wq, const u16* xnt, u16* qkvt, u16* vnat) {
    int bid = blockIdx.x;
    int b = bid / 96;
    int r2 = bid % 96;
    int mt = r2 >> 5, nt = r2 & 31;
    int tid = threadIdx.x;
    int w = tid >> 6, lane = tid & 63, lr = lane & 15, lg = lane >> 4;
    int wr = w >> 1, wc = w & 1;
    int ob = mt * 128 + wr * 64;
    int nb = nt * 128 + wc * 64;
    f32x4 acc[4][4];
#pragma unroll
    for (int mi = 0; mi < 4; mi++)
#pragma unroll
        for (int ni = 0; ni < 4; ni++) acc[mi][ni] = (f32x4){0.f, 0.f, 0.f, 0.f};
    const u16* apan = wq + (ob + lr) * 256 + lg * 8;
    const u16* bpan = xnt + ((size_t)(b * 4096 + nb + lr)) * 256 + lg * 8;
#pragma unroll
    for (int kk = 0; kk < 256; kk += 32) {
        bf16x8 af[4], bfv[4];
#pragma unroll
        for (int mi = 0; mi < 4; mi++) af[mi] = *(const bf16x8*)(apan + mi * 16 * 256 + kk);
#pragma unroll
        for (int ni = 0; ni < 4; ni++) bfv[ni] = *(const bf16x8*)(bpan + ni * 16 * 256 + kk);
#pragma unroll
        for (int mi = 0; mi < 4; mi++)
#pragma unroll
            for (int ni = 0; ni < 4; ni++) acc[mi][ni] = MFMA16(af[mi], bfv[ni], acc[mi][ni]);
    }
    if (mt < 2) {
#pragma unroll
        for (int mi = 0; mi < 4; mi++)
#pragma unroll
            for (int ni = 0; ni < 4; ni++) {
                int o0 = ob + mi * 16 + lg * 4;
                int n = nb + ni * 16 + lr;
                ushort4 pk;
                pk.x = f2bf(acc[mi][ni][0]);
                pk.y = f2bf(acc[mi][ni][1]);
                pk.z = f2bf(acc[mi][ni][2]);
                pk.w = f2bf(acc[mi][ni][3]);
                *(ushort4*)(qkvt + ((size_t)(b * 4096 + n)) * 256 + o0) = pk;
            }
    } else {
#pragma unroll
        for (int mi = 0; mi < 4; mi++)
#pragma unroll
            for (int ni = 0; ni < 4; ni++) {
                int n = nb + ni * 16 + lr;
#pragma unroll
                for (int r = 0; r < 4; r++) {
                    int o = ob + mi * 16 + lg * 4 + r - 256;
                    vnat[((size_t)(b * 128 + o)) * 4096 + n] = f2bf(acc[mi][ni][r]);
                }
            }
    }
}

// ---------------- flash attention: per (b,h,i-block of 64). 4 waves x 16 q-rows.
// Q,K from qkvt (b,n,256): q at o=h*32, k at o=128+h*32. V from vnat (b,128,n).
__global__ __launch_bounds__(256) void k_attn(const u16* qkvt, const u16* vnat, u16* attnt) {
    int bid = blockIdx.x;
    int ib = bid & 63;
    int h = (bid >> 6) & 3;
    int b = bid >> 8;
    int tid = threadIdx.x;
    int w = tid >> 6, lane = tid & 63, lr = lane & 15, lg = lane >> 4;
    int i0 = ib * 64 + w * 16;

    __shared__ __align__(16) u16 p_lds[4][16][40];   // per-wave P tile, padded rows (80B, 16B-aligned)

    bf16x8 qf = *(const bf16x8*)(qkvt + ((size_t)(b * 4096 + i0 + lr)) * 256 + h * 32 + lg * 8);

    f32x4 o0 = {0.f, 0.f, 0.f, 0.f}, o1 = {0.f, 0.f, 0.f, 0.f};
    float m_[4], l_[4];
#pragma unroll
    for (int r = 0; r < 4; r++) { m_[r] = -1e30f; l_[r] = 0.f; }

    const float sl = 0.25503485f;  // (1/sqrt(32)) * log2(e): softmax in exp2 domain
    const u16* kpanel = qkvt + 128 + h * 32 + lg * 8;
    const u16* vpanel = vnat + ((size_t)((b * 4 + h) * 32)) * 4096;

    for (int jb = 0; jb < 4096; jb += 32) {
        const u16* kp = kpanel + ((size_t)(b * 4096 + jb + lr)) * 256;
        bf16x8 kf0 = *(const bf16x8*)(kp);
        bf16x8 kf1 = *(const bf16x8*)(kp + 16 * 256);
        f32x4 z = {0.f, 0.f, 0.f, 0.f};
        f32x4 s0 = MFMA16(qf, kf0, z);   // rows i (lg*4+r), cols j (lr)
        f32x4 s1 = MFMA16(qf, kf1, z);   // cols j+16

        float tm[4];
#pragma unroll
        for (int r = 0; r < 4; r++) {
            s0[r] *= sl;
            s1[r] *= sl;
            float t = fmaxf(s0[r], s1[r]);
            t = fmaxf(t, __shfl_xor(t, 1));
            t = fmaxf(t, __shfl_xor(t, 2));
            t = fmaxf(t, __shfl_xor(t, 4));
            t = fmaxf(t, __shfl_xor(t, 8));
            tm[r] = t;
        }
#pragma unroll
        for (int r = 0; r < 4; r++) {
            float mn = fmaxf(m_[r], tm[r]);
            float corr = exp2f(m_[r] - mn);
            m_[r] = mn;
            float p0 = exp2f(s0[r] - mn);
            float p1 = exp2f(s1[r] - mn);
            float rs = p0 + p1;
            rs += __shfl_xor(rs, 1);
            rs += __shfl_xor(rs, 2);
            rs += __shfl_xor(rs, 4);
            rs += __shfl_xor(rs, 8);
            l_[r] = l_[r] * corr + rs;
            o0[r] *= corr;
            o1[r] *= corr;
            p_lds[w][lg * 4 + r][lr] = f2bf(p0);
            p_lds[w][lg * 4 + r][16 + lr] = f2bf(p1);
        }
        // wave-private LDS: in-order DS + compiler lgkmcnt handles write->read dependency
        bf16x8 pa = *(const bf16x8*)&p_lds[w][lr][lg * 8];
        const u16* vp = vpanel + lr * 4096 + jb + lg * 8;
        bf16x8 vb0 = *(const bf16x8*)(vp);
        bf16x8 vb1 = *(const bf16x8*)(vp + 16 * 4096);
        o0 = MFMA16(pa, vb0, o0);
        o1 = MFMA16(pa, vb1, o1);
    }
#pragma unroll
    for (int r = 0; r < 4; r++) {
        float inv = 1.0f / l_[r];
        int i = i0 + lg * 4 + r;
        u16* orow = attnt + ((size_t)(b * 4096 + i)) * 128 + h * 32;
        orow[lr] = f2bf(o0[r] * inv);
        orow[16 + lr] = f2bf(o1[r] * inv);
    }
}

// ---------------- proj GEMM + bias + residual: proj_w(256x128) x attnt^T + pb + x -> out f32
// grid 128 = b(2) x mt(2) x nt(32)
__global__ __launch_bounds__(256) void k_proj(const u16* wp, const u16* attnt, const float* pb,
                                              const float* x, float* out) {
    int bid = blockIdx.x;
    int b = bid >> 6;
    int r2 = bid & 63;
    int mt = r2 >> 5, nt = r2 & 31;
    int tid = threadIdx.x;
    int w = tid >> 6, lane = tid & 63, lr = lane & 15, lg = lane >> 4;
    int wr = w >> 1, wc = w & 1;
    int cb = mt * 128 + wr * 64;
    int nb = nt * 128 + wc * 64;
    f32x4 acc[4][4];
#pragma unroll
    for (int mi = 0; mi < 4; mi++)
#pragma unroll
        for (int ni = 0; ni < 4; ni++) acc[mi][ni] = (f32x4){0.f, 0.f, 0.f, 0.f};
    const u16* apan = wp + (cb + lr) * 128 + lg * 8;
    const u16* bpan = attnt + ((size_t)(b * 4096 + nb + lr)) * 128 + lg * 8;
#pragma unroll
    for (int kk = 0; kk < 128; kk += 32) {
        bf16x8 af[4], bfv[4];
#pragma unroll
        for (int mi = 0; mi < 4; mi++) af[mi] = *(const bf16x8*)(apan + mi * 16 * 128 + kk);
#pragma unroll
        for (int ni = 0; ni < 4; ni++) bfv[ni] = *(const bf16x8*)(bpan + ni * 16 * 128 + kk);
#pragma unroll
        for (int mi = 0; mi < 4; mi++)
#pragma unroll
            for (int ni = 0; ni < 4; ni++) acc[mi][ni] = MFMA16(af[mi], bfv[ni], acc[mi][ni]);
    }
#pragma unroll
    for (int mi = 0; mi < 4; mi++)
#pragma unroll
        for (int ni = 0; ni < 4; ni++) {
            int n = nb + ni * 16 + lr;
#pragma unroll
            for (int r = 0; r < 4; r++) {
                int c = cb + mi * 16 + lg * 4 + r;
                size_t idx = ((size_t)(b * 256 + c)) * 4096 + n;
                out[idx] = acc[mi][ni][r] + pb[c] + x[idx];
            }
        }
}

extern "C" void kernel_launch(void* const* d_in, const int* in_sizes, int n_in,
                              void* d_out, int out_size, void* d_ws, size_t ws_size,
                              hipStream_t stream) {
    const float* x = (const float*)d_in[0];
    const float* nw = (const float*)d_in[1];
    const float* nbv = (const float*)d_in[2];
    const float* qw = (const float*)d_in[3];
    const float* pw = (const float*)d_in[4];
    const float* pb = (const float*)d_in[5];
    float* out = (float*)d_out;
    char* ws = (char*)d_ws;

    float* psum = (float*)(ws + 0);          // 256 f32
    float* psumsq = (float*)(ws + 1024);     // 256 f32
    float* meanb = (float*)(ws + 2048);      // 16 f32
    float* rstdb = (float*)(ws + 2112);      // 16 f32
    u16* qwb = (u16*)(ws + 4096);            // 384*256 bf16
    u16* pwb = (u16*)(ws + 200704);          // 256*128 bf16
    u16* xnt = (u16*)(ws + 266240);          // (2,4096,256) bf16
    u16* qkvt = (u16*)(ws + 4460544);        // (2,4096,256) bf16 (q|k, n-major)
    u16* vnat = (u16*)(ws + 8654848);        // (2,128,4096) bf16
    u16* attnt = (u16*)(ws + 10752000);      // (2,4096,128) bf16

    k_wconv<<<64, 256, 0, stream>>>(qw, pw, qwb, pwb);
    k_stats1<<<256, 256, 0, stream>>>(x, psum, psumsq);
    k_stats2<<<1, 64, 0, stream>>>(psum, psumsq, meanb, rstdb);
    k_normt<<<2048, 256, 0, stream>>>(x, nw, nbv, meanb, rstdb, xnt);
    k_qkv<<<192, 256, 0, stream>>>(qwb, xnt, qkvt, vnat);
    k_attn<<<512, 256, 0, stream>>>(qkvt, vnat, attnt);
    k_proj<<<128, 256, 0, stream>>>(pwb, attnt, pb, x, out);
}

// Round 2
// 221.559 us; speedup vs baseline: 1.2223x; 1.2223x over previous
//
#include <hip/hip_runtime.h>

typedef unsigned short u16;
typedef __attribute__((ext_vector_type(8))) short bf16x8;
typedef __attribute__((ext_vector_type(4))) float f32x4;

#define MFMA16(a, b, c) __builtin_amdgcn_mfma_f32_16x16x32_bf16(a, b, c, 0, 0, 0)

__device__ inline u16 f2bf(float f) {
    unsigned u = __float_as_uint(f);
    u = u + 0x7FFFu + ((u >> 16) & 1u);
    return (u16)(u >> 16);
}

__device__ inline float fast_exp2(float x) {
#if __has_builtin(__builtin_amdgcn_exp2f)
    return __builtin_amdgcn_exp2f(x);
#else
    return exp2f(x);
#endif
}

__device__ inline unsigned cvtpk(float lo, float hi) {
    unsigned r;
    asm("v_cvt_pk_bf16_f32 %0, %1, %2" : "=v"(r) : "v"(lo), "v"(hi));
    return r;
}

// j-permutation within each 64-block: jloc = 16t + 4lg + r  ->  32(t&1) + 8lg + 4(t>>1) + r
// (applied to V columns so PV sums match the QK^T-swapped fragment order)
__device__ inline int vperm(int j) {
    return ((j >> 4) & 1) * 32 + ((j >> 2) & 3) * 8 + ((j >> 5) & 1) * 4 + (j & 3);
}

// ---------------- weight conversion: qkv_w (384x256) + proj_w (256x128) -> bf16
__global__ __launch_bounds__(256) void k_wconv(const float* qw, const float* pw, u16* qwb, u16* pwb) {
    int tid = blockIdx.x * 256 + threadIdx.x;
    int base = tid * 8;
    const float* src;
    u16* dst;
    if (base < 98304) { src = qw + base; dst = qwb + base; }
    else { src = pw + (base - 98304); dst = pwb + (base - 98304); }
    float4 v0 = *(const float4*)(src);
    float4 v1 = *(const float4*)(src + 4);
    ushort4 o0, o1;
    o0.x = f2bf(v0.x); o0.y = f2bf(v0.y); o0.z = f2bf(v0.z); o0.w = f2bf(v0.w);
    o1.x = f2bf(v1.x); o1.y = f2bf(v1.y); o1.z = f2bf(v1.z); o1.w = f2bf(v1.w);
    *(ushort4*)(dst) = o0;
    *(ushort4*)(dst + 4) = o1;
}

// ---------------- groupnorm stats stage 1
__global__ __launch_bounds__(256) void k_stats1(const float* x, float* psum, float* psumsq) {
    int bid = blockIdx.x;
    int gi = bid >> 4, s = bid & 15;
    const float* base = x + (size_t)gi * 131072 + s * 8192;
    int t = threadIdx.x;
    float s1 = 0.f, s2 = 0.f;
#pragma unroll
    for (int it = 0; it < 8; it++) {
        float4 v = *(const float4*)(base + it * 1024 + t * 4);
        s1 += (v.x + v.y) + (v.z + v.w);
        s2 += (v.x * v.x + v.y * v.y) + (v.z * v.z + v.w * v.w);
    }
    for (int msk = 1; msk < 64; msk <<= 1) {
        s1 += __shfl_xor(s1, msk);
        s2 += __shfl_xor(s2, msk);
    }
    __shared__ float r1[4], r2[4];
    int w = t >> 6;
    if ((t & 63) == 0) { r1[w] = s1; r2[w] = s2; }
    __syncthreads();
    if (t == 0) {
        psum[bid] = (r1[0] + r1[1]) + (r1[2] + r1[3]);
        psumsq[bid] = (r2[0] + r2[1]) + (r2[2] + r2[3]);
    }
}

// ---------------- groupnorm stats stage 2
__global__ void k_stats2(const float* psum, const float* psumsq, float* meanb, float* rstdb) {
    int t = threadIdx.x;
    if (t < 16) {
        float s1 = 0.f, s2 = 0.f;
        for (int i = 0; i < 16; i++) { s1 += psum[t * 16 + i]; s2 += psumsq[t * 16 + i]; }
        float mu = s1 * (1.0f / 131072.0f);
        float var = s2 * (1.0f / 131072.0f) - mu * mu;
        meanb[t] = mu;
        rstdb[t] = rsqrtf(var + 1e-5f);
    }
}

// ---------------- normalize + transpose: x (b,c,n) f32 -> xnt (b,n,c) bf16
__global__ __launch_bounds__(256) void k_normt(const float* x, const float* gw, const float* gb,
                                               const float* meanb, const float* rstdb, u16* xnt) {
    int bid = blockIdx.x;
    int b = bid >> 10, ct = (bid >> 7) & 7, nt = bid & 127;
    int t = threadIdx.x;
    int r = t >> 3, q = t & 7;
    __shared__ float tile[32][33];
    int gi = b * 8 + ct;
    float mu = meanb[gi], rs = rstdb[gi];
    int c = ct * 32 + r;
    float wv = gw[c] * rs;
    float bv = gb[c] - mu * wv;
    float4 v = *(const float4*)(x + ((size_t)(b * 256 + c)) * 4096 + nt * 32 + q * 4);
    tile[r][q * 4 + 0] = v.x * wv + bv;
    tile[r][q * 4 + 1] = v.y * wv + bv;
    tile[r][q * 4 + 2] = v.z * wv + bv;
    tile[r][q * 4 + 3] = v.w * wv + bv;
    __syncthreads();
    int cq = q * 4;
    ushort4 o;
    o.x = f2bf(tile[cq + 0][r]);
    o.y = f2bf(tile[cq + 1][r]);
    o.z = f2bf(tile[cq + 2][r]);
    o.w = f2bf(tile[cq + 3][r]);
    *(ushort4*)(xnt + ((size_t)(b * 4096 + nt * 32 + r)) * 256 + ct * 32 + cq) = o;
}

// ---------------- QKV GEMM. Q pre-scaled by scale*log2e; V columns bit-permuted per 64-block.
__global__ __launch_bounds__(256) void k_qkv(const u16* __restrict__ wq, const u16* __restrict__ xnt,
                                             u16* __restrict__ qkvt, u16* __restrict__ vnat) {
    int bid = blockIdx.x;
    int b = bid / 96;
    int r2 = bid % 96;
    int mt = r2 >> 5, nt = r2 & 31;
    int tid = threadIdx.x;
    int w = tid >> 6, lane = tid & 63, lr = lane & 15, lg = lane >> 4;
    int wr = w >> 1, wc = w & 1;
    int ob = mt * 128 + wr * 64;
    int nb = nt * 128 + wc * 64;
    f32x4 acc[4][4];
#pragma unroll
    for (int mi = 0; mi < 4; mi++)
#pragma unroll
        for (int ni = 0; ni < 4; ni++) acc[mi][ni] = (f32x4){0.f, 0.f, 0.f, 0.f};
    const u16* apan = wq + (ob + lr) * 256 + lg * 8;
    const u16* bpan = xnt + ((size_t)(b * 4096 + nb + lr)) * 256 + lg * 8;
#pragma unroll
    for (int kk = 0; kk < 256; kk += 32) {
        bf16x8 af[4], bfv[4];
#pragma unroll
        for (int mi = 0; mi < 4; mi++) af[mi] = *(const bf16x8*)(apan + mi * 16 * 256 + kk);
#pragma unroll
        for (int ni = 0; ni < 4; ni++) bfv[ni] = *(const bf16x8*)(bpan + ni * 16 * 256 + kk);
#pragma unroll
        for (int mi = 0; mi < 4; mi++)
#pragma unroll
            for (int ni = 0; ni < 4; ni++) acc[mi][ni] = MFMA16(af[mi], bfv[ni], acc[mi][ni]);
    }
    if (mt == 0) {
        const float sl = 0.25503485f;  // (1/sqrt(32)) * log2(e) folded into Q
#pragma unroll
        for (int mi = 0; mi < 4; mi++)
#pragma unroll
            for (int ni = 0; ni < 4; ni++)
#pragma unroll
                for (int r = 0; r < 4; r++) acc[mi][ni][r] *= sl;
    }
    if (mt < 2) {
#pragma unroll
        for (int mi = 0; mi < 4; mi++)
#pragma unroll
            for (int ni = 0; ni < 4; ni++) {
                int o0 = ob + mi * 16 + lg * 4;
                int n = nb + ni * 16 + lr;
                ushort4 pk;
                pk.x = f2bf(acc[mi][ni][0]);
                pk.y = f2bf(acc[mi][ni][1]);
                pk.z = f2bf(acc[mi][ni][2]);
                pk.w = f2bf(acc[mi][ni][3]);
                *(ushort4*)(qkvt + ((size_t)(b * 4096 + n)) * 256 + o0) = pk;
            }
    } else {
#pragma unroll
        for (int mi = 0; mi < 4; mi++)
#pragma unroll
            for (int ni = 0; ni < 4; ni++) {
                int n = nb + ni * 16 + lr;
                int np = (n & ~63) | vperm(n & 63);
#pragma unroll
                for (int r = 0; r < 4; r++) {
                    int o = ob + mi * 16 + lg * 4 + r - 256;
                    vnat[((size_t)(b * 128 + o)) * 4096 + np] = f2bf(acc[mi][ni][r]);
                }
            }
    }
}

// ---------------- flash attention, swapped-operand QK^T, LDS-free.
// Per (b,h,i-block of 64). 4 waves x 16 q-rows. j-block = 64 (4 QK + 4 PV MFMAs).
// Lane layout after swap: S^T[j][i] with i = lr, j(within 64) = 16t + 4lg + r.
// V columns pre-permuted so lane's P values form its PV B-fragment with zero movement.
__global__ __launch_bounds__(256) void k_attn(const u16* __restrict__ qkvt, const u16* __restrict__ vnat,
                                              u16* __restrict__ attnt) {
    int bid = blockIdx.x;
    int ib = bid & 63;
    int h = (bid >> 6) & 3;
    int b = bid >> 8;
    int tid = threadIdx.x;
    int w = tid >> 6, lane = tid & 63, lr = lane & 15, lg = lane >> 4;
    int i0 = ib * 64 + w * 16;

    // Q^T fragment (B-operand): col i = lr, k = lg*8..+7. Pre-scaled in k_qkv.
    bf16x8 qf = *(const bf16x8*)(qkvt + ((size_t)(b * 4096 + i0 + lr)) * 256 + h * 32 + lg * 8);

    f32x4 oa0 = {0.f, 0.f, 0.f, 0.f}, oa1 = {0.f, 0.f, 0.f, 0.f};
    float m_ = -1e30f, l_ = 0.f;

    const u16* kbase = qkvt + (size_t)b * 4096 * 256 + (size_t)lr * 256 + 128 + h * 32 + lg * 8;
    const u16* vbase = vnat + ((size_t)((b * 4 + h) * 32 + lr)) * 4096 + lg * 8;

    for (int jb = 0; jb < 4096; jb += 64) {
        const u16* kp = kbase + (size_t)jb * 256;
        bf16x8 kf0 = *(const bf16x8*)(kp);
        bf16x8 kf1 = *(const bf16x8*)(kp + 16 * 256);
        bf16x8 kf2 = *(const bf16x8*)(kp + 32 * 256);
        bf16x8 kf3 = *(const bf16x8*)(kp + 48 * 256);
        const u16* vp = vbase + jb;
        bf16x8 va00 = *(const bf16x8*)(vp);                 // d-tile 0, pv-mfma 0
        bf16x8 va01 = *(const bf16x8*)(vp + 32);            // d-tile 0, pv-mfma 1
        bf16x8 va10 = *(const bf16x8*)(vp + 16 * 4096);     // d-tile 1, pv-mfma 0
        bf16x8 va11 = *(const bf16x8*)(vp + 16 * 4096 + 32);
        f32x4 z = {0.f, 0.f, 0.f, 0.f};
        f32x4 s0 = MFMA16(kf0, qf, z);   // j = jb + 0..15:  lane holds j=16*0+4lg+r, i=lr
        f32x4 s1 = MFMA16(kf1, qf, z);
        f32x4 s2 = MFMA16(kf2, qf, z);
        f32x4 s3 = MFMA16(kf3, qf, z);

        // in-lane row max over 16 values + 2-shuffle reduce across the 4 lg-groups
        float tm = fmaxf(
            fmaxf(fmaxf(fmaxf(s0[0], s0[1]), fmaxf(s0[2], s0[3])),
                  fmaxf(fmaxf(s1[0], s1[1]), fmaxf(s1[2], s1[3]))),
            fmaxf(fmaxf(fmaxf(s2[0], s2[1]), fmaxf(s2[2], s2[3])),
                  fmaxf(fmaxf(s3[0], s3[1]), fmaxf(s3[2], s3[3]))));
        tm = fmaxf(tm, __shfl_xor(tm, 16));
        tm = fmaxf(tm, __shfl_xor(tm, 32));

        if (__any(tm > m_)) {           // wave-uniform rescale, skipped once max stabilizes
            float mn = fmaxf(m_, tm);
            float corr = fast_exp2(m_ - mn);
            m_ = mn;
            l_ *= corr;
            oa0[0] *= corr; oa0[1] *= corr; oa0[2] *= corr; oa0[3] *= corr;
            oa1[0] *= corr; oa1[1] *= corr; oa1[2] *= corr; oa1[3] *= corr;
        }

        float p00 = fast_exp2(s0[0] - m_), p01 = fast_exp2(s0[1] - m_);
        float p02 = fast_exp2(s0[2] - m_), p03 = fast_exp2(s0[3] - m_);
        float p10 = fast_exp2(s1[0] - m_), p11 = fast_exp2(s1[1] - m_);
        float p12 = fast_exp2(s1[2] - m_), p13 = fast_exp2(s1[3] - m_);
        float p20 = fast_exp2(s2[0] - m_), p21 = fast_exp2(s2[1] - m_);
        float p22 = fast_exp2(s2[2] - m_), p23 = fast_exp2(s2[3] - m_);
        float p30 = fast_exp2(s3[0] - m_), p31 = fast_exp2(s3[1] - m_);
        float p32 = fast_exp2(s3[2] - m_), p33 = fast_exp2(s3[3] - m_);

        float rs = (((p00 + p01) + (p02 + p03)) + ((p10 + p11) + (p12 + p13)))
                 + (((p20 + p21) + (p22 + p23)) + ((p30 + p31) + (p32 + p33)));
        rs += __shfl_xor(rs, 16);
        rs += __shfl_xor(rs, 32);
        l_ += rs;

        // pack to PV B-fragments: mfma0 <- t=0,2 ; mfma1 <- t=1,3 (matches vperm)
        union { bf16x8 v; unsigned u[4]; } pb0, pb1;
        pb0.u[0] = cvtpk(p00, p01); pb0.u[1] = cvtpk(p02, p03);
        pb0.u[2] = cvtpk(p20, p21); pb0.u[3] = cvtpk(p22, p23);
        pb1.u[0] = cvtpk(p10, p11); pb1.u[1] = cvtpk(p12, p13);
        pb1.u[2] = cvtpk(p30, p31); pb1.u[3] = cvtpk(p32, p33);

        oa0 = MFMA16(va00, pb0.v, oa0);
        oa0 = MFMA16(va01, pb1.v, oa0);
        oa1 = MFMA16(va10, pb0.v, oa1);
        oa1 = MFMA16(va11, pb1.v, oa1);
    }

    float inv = 1.0f / l_;
    ushort4 st0, st1;
    st0.x = f2bf(oa0[0] * inv); st0.y = f2bf(oa0[1] * inv);
    st0.z = f2bf(oa0[2] * inv); st0.w = f2bf(oa0[3] * inv);
    st1.x = f2bf(oa1[0] * inv); st1.y = f2bf(oa1[1] * inv);
    st1.z = f2bf(oa1[2] * inv); st1.w = f2bf(oa1[3] * inv);
    u16* orow = attnt + ((size_t)(b * 4096 + i0 + lr)) * 128 + h * 32 + 4 * lg;
    *(ushort4*)(orow) = st0;          // d = 4lg+0..3  (O^T row d, col i: d=4lg+reg, i=lr)
    *(ushort4*)(orow + 16) = st1;     // d = 16+4lg+0..3
}

// ---------------- proj GEMM + bias + residual
__global__ __launch_bounds__(256) void k_proj(const u16* __restrict__ wp, const u16* __restrict__ attnt,
                                              const float* __restrict__ pb, const float* __restrict__ x,
                                              float* __restrict__ out) {
    int bid = blockIdx.x;
    int b = bid >> 6;
    int r2 = bid & 63;
    int mt = r2 >> 5, nt = r2 & 31;
    int tid = threadIdx.x;
    int w = tid >> 6, lane = tid & 63, lr = lane & 15, lg = lane >> 4;
    int wr = w >> 1, wc = w & 1;
    int cb = mt * 128 + wr * 64;
    int nb = nt * 128 + wc * 64;
    f32x4 acc[4][4];
#pragma unroll
    for (int mi = 0; mi < 4; mi++)
#pragma unroll
        for (int ni = 0; ni < 4; ni++) acc[mi][ni] = (f32x4){0.f, 0.f, 0.f, 0.f};
    const u16* apan = wp + (cb + lr) * 128 + lg * 8;
    const u16* bpan = attnt + ((size_t)(b * 4096 + nb + lr)) * 128 + lg * 8;
#pragma unroll
    for (int kk = 0; kk < 128; kk += 32) {
        bf16x8 af[4], bfv[4];
#pragma unroll
        for (int mi = 0; mi < 4; mi++) af[mi] = *(const bf16x8*)(apan + mi * 16 * 128 + kk);
#pragma unroll
        for (int ni = 0; ni < 4; ni++) bfv[ni] = *(const bf16x8*)(bpan + ni * 16 * 128 + kk);
#pragma unroll
        for (int mi = 0; mi < 4; mi++)
#pragma unroll
            for (int ni = 0; ni < 4; ni++) acc[mi][ni] = MFMA16(af[mi], bfv[ni], acc[mi][ni]);
    }
#pragma unroll
    for (int mi = 0; mi < 4; mi++)
#pragma unroll
        for (int ni = 0; ni < 4; ni++) {
            int n = nb + ni * 16 + lr;
#pragma unroll
            for (int r = 0; r < 4; r++) {
                int c = cb + mi * 16 + lg * 4 + r;
                size_t idx = ((size_t)(b * 256 + c)) * 4096 + n;
                out[idx] = acc[mi][ni][r] + pb[c] + x[idx];
            }
        }
}

extern "C" void kernel_launch(void* const* d_in, const int* in_sizes, int n_in,
                              void* d_out, int out_size, void* d_ws, size_t ws_size,
                              hipStream_t stream) {
    const float* x = (const float*)d_in[0];
    const float* nw = (const float*)d_in[1];
    const float* nbv = (const float*)d_in[2];
    const float* qw = (const float*)d_in[3];
    const float* pw = (const float*)d_in[4];
    const float* pb = (const float*)d_in[5];
    float* out = (float*)d_out;
    char* ws = (char*)d_ws;

    float* psum = (float*)(ws + 0);
    float* psumsq = (float*)(ws + 1024);
    float* meanb = (float*)(ws + 2048);
    float* rstdb = (float*)(ws + 2112);
    u16* qwb = (u16*)(ws + 4096);
    u16* pwb = (u16*)(ws + 200704);
    u16* xnt = (u16*)(ws + 266240);
    u16* qkvt = (u16*)(ws + 4460544);
    u16* vnat = (u16*)(ws + 8654848);
    u16* attnt = (u16*)(ws + 10752000);

    k_wconv<<<64, 256, 0, stream>>>(qw, pw, qwb, pwb);
    k_stats1<<<256, 256, 0, stream>>>(x, psum, psumsq);
    k_stats2<<<1, 64, 0, stream>>>(psum, psumsq, meanb, rstdb);
    k_normt<<<2048, 256, 0, stream>>>(x, nw, nbv, meanb, rstdb, xnt);
    k_qkv<<<192, 256, 0, stream>>>(qwb, xnt, qkvt, vnat);
    k_attn<<<512, 256, 0, stream>>>(qkvt, vnat, attnt);
    k_proj<<<128, 256, 0, stream>>>(pwb, attnt, pb, x, out);
}